// Round 4
// baseline (286.253 us; speedup 1.0000x reference)
//
#include <hip/hip_runtime.h>

// NRC fused encode + 7-layer W=64 MLP, f16 MFMA (16x16x32), fp32 accumulate.
// Fragment maps (gfx950 16x16x32 f16, verified):
//   A[m=lane&15][k=(lane>>4)*8+j]   (A = weight rows, M = out features)
//   B[k=(lane>>4)*8+j][n=lane&15]   (B = h^T, N = samples)
//   D[row=(lane>>4)*4+r][col=lane&15]
// h stored in LDS in B-fragment-native chunks: chunk fc=(kt*4+q) holds
// features f=fc*8..fc*8+7 for each of 16 samples, 16B per (chunk,row).
//
// R4: R3 + zero-cost compiler memory fences at LDS phase boundaries.
//     R3's 9791 absmax was stale-LDS reads: with the encode fully inlined
//     (no OCML calls acting as accidental scheduling fences), the compiler
//     reordered encode ds_writes vs layer-0 ds_reads (distinct ext-vector
//     TBAA tags). LDS is in-order per wave, so asm memory clobbers suffice
//     for the wave-private tiles — no s_waitcnt / s_barrier needed.

typedef _Float16 f16;
typedef f16 f16x2 __attribute__((ext_vector_type(2)));
typedef f16 f16x4 __attribute__((ext_vector_type(4)));
typedef f16 f16x8 __attribute__((ext_vector_type(8)));
typedef float f32x4 __attribute__((ext_vector_type(4)));

#define MFMA16(A, B, C) __builtin_amdgcn_mfma_f32_16x16x32_f16(A, B, C, 0, 0, 0)
#define LDS_FENCE() __asm__ volatile("" ::: "memory")

static constexpr int TILES = 4;                  // 16-sample tiles per wave
static constexpr int WAVES = 2;                  // waves per block
static constexpr int BLOCK = WAVES * 64;         // 128 threads
static constexpr int SPB   = WAVES * TILES * 16; // 128 samples per block

__device__ __forceinline__ f16x2 pkh(float a, float b) {
    return __builtin_bit_cast(f16x2, __builtin_amdgcn_cvt_pkrtz(a, b));
}

__device__ __forceinline__ f16x8 pack8(const float* f) {
    f16x2 a = pkh(f[0], f[1]);
    f16x2 b = pkh(f[2], f[3]);
    f16x2 c = pkh(f[4], f[5]);
    f16x2 d = pkh(f[6], f[7]);
    f16x8 v;
    v[0] = a[0]; v[1] = a[1]; v[2] = b[0]; v[3] = b[1];
    v[4] = c[0]; v[5] = c[1]; v[6] = d[0]; v[7] = d[1];
    return v;
}

__device__ __forceinline__ f16x8 load_wfrag(const float* __restrict__ Wl, int row, int k0) {
    const f32x4 lo = *(const f32x4*)(Wl + row * 64 + k0);
    const f32x4 hi = *(const f32x4*)(Wl + row * 64 + k0 + 4);
    float t[8] = {lo[0], lo[1], lo[2], lo[3], hi[0], hi[1], hi[2], hi[3]};
    return pack8(t);
}

// atan2(y,x) / (2*pi)  in (-0.5, 0.5]; |err| ~ 3e-8 rev
__device__ __forceinline__ float fast_atan2_rev(float y, float x) {
    const float ax = __builtin_fabsf(x), ay = __builtin_fabsf(y);
    const float mx = fmaxf(ax, ay), mn = fminf(ax, ay);
    const float a = mn * __builtin_amdgcn_rcpf(fmaxf(mx, 1e-30f));
    const float s = a * a;
    float r = a * (0.99997726f + s * (-0.33262347f + s * (0.19354346f +
              s * (-0.11643287f + s * (0.05265332f - s * 0.01172120f)))));
    if (ay > ax) r = 1.5707963268f - r;
    if (x < 0.0f) r = 3.1415926536f - r;
    r = (y < 0.0f) ? -r : r;
    return r * 0.15915494309189535f;
}

// acos(x), |err| <= 6.8e-5 rad
__device__ __forceinline__ float fast_acos(float x) {
    const float ax = __builtin_fabsf(x);
    const float t = __builtin_amdgcn_sqrtf(1.0f - ax);
    const float p = t * (1.5707288f + ax * (-0.2121144f +
                    ax * (0.0742610f - ax * 0.0187293f)));
    return (x < 0.0f) ? (3.1415926536f - p) : p;
}

__global__ __launch_bounds__(BLOCK, 4) void nrc_mlp_kernel(
    const float* __restrict__ P,  const float* __restrict__ WI,
    const float* __restrict__ NV, const float* __restrict__ AL,
    const float* __restrict__ BE, const float* __restrict__ RR,
    const float* __restrict__ W0, const float* __restrict__ W1,
    const float* __restrict__ W2, const float* __restrict__ W3,
    const float* __restrict__ W4, const float* __restrict__ W5,
    const float* __restrict__ W6, float* __restrict__ Out)
{
    // LDS: [0,2048) W6 frags | h tiles | ab (alpha+beta) -> 20480 B total
    __shared__ __attribute__((aligned(16)))
        unsigned char smem[2048 + WAVES * TILES * 2048 + WAVES * TILES * 16 * 16];

    const int tid  = threadIdx.x;
    const int lane = tid & 63;
    const int w    = tid >> 6;
    const int q    = lane >> 4;
    const int m    = lane & 15;

    unsigned char* const w6b = smem;
    unsigned char* const hb  = smem + 2048 + w * (TILES * 2048);
    unsigned char* const abb = smem + 2048 + WAVES * TILES * 2048 + w * (TILES * 16 * 16);

    const int wave_base = (int)blockIdx.x * SPB + w * (TILES * 16);

    // ---- stage W6 fragments into LDS (rows padded 3 -> 16 with zeros) ----
    {
        const int kt = tid >> 6;   // 0..1 (128 threads)
        const int l2 = tid & 63;
        const int mm = l2 & 15, qq = l2 >> 4;
        f16x8 v;
#pragma unroll
        for (int j = 0; j < 8; ++j) {
            const int k = kt * 32 + qq * 8 + j;
            const float val = (mm < 3) ? W6[mm * 64 + k] : 0.0f;
            v[j] = (f16)val;
        }
        *(f16x8*)(w6b + (kt * 64 + l2) * 16) = v;
    }
    __syncthreads();

    // ---- encode: 64 samples, one per lane ----
    {
        const int s = wave_base + lane;      // global sample

        float pv[3], wv[3], nv[3], av[3], bv[3];
#pragma unroll
        for (int d = 0; d < 3; ++d) {
            pv[d] = P [s * 3 + d];
            wv[d] = WI[s * 3 + d];
            nv[d] = NV[s * 3 + d];
            av[d] = AL[s * 3 + d];
            bv[d] = BE[s * 3 + d];
        }
        const float rv = RR[s];

        float feat[64];
        // frequency embedding: sin(pi*p*2^k) = v_sin(fract(p*2^(k-1))) [revolutions]
#pragma unroll
        for (int d = 0; d < 3; ++d) {
#pragma unroll
            for (int k = 0; k < 6; ++k) {
                const float rev = pv[d] * (0.5f * (float)(1 << k));
                const float fr  = __builtin_amdgcn_fractf(rev);
                feat[d * 12 + k]     = __builtin_amdgcn_sinf(fr);
                feat[d * 12 + 6 + k] = __builtin_amdgcn_cosf(fr);
            }
        }
        // sph + one-blob for wi (36..43) and n (44..51)
#pragma unroll
        for (int which = 0; which < 2; ++which) {
            const float* dv = (which == 0) ? wv : nv;
            const int fo = 36 + which * 8;
            const float nr = __builtin_amdgcn_sqrtf(dv[0]*dv[0] + dv[1]*dv[1] + dv[2]*dv[2]) + 1e-8f;
            const float u  = fast_atan2_rev(dv[1], dv[0]) + 0.5f;
            float zc = dv[2] * __builtin_amdgcn_rcpf(nr);
            zc = fminf(fmaxf(zc, -1.0f + 1e-6f), 1.0f - 1e-6f);
            const float vv = fast_acos(zc) * 0.3183098861837907f;
#pragma unroll
            for (int i = 0; i < 4; ++i) {
                const float cc = (i + 0.5f) * 0.25f;
                const float du = u - cc, dvv = vv - cc;
                feat[fo + i]     = __expf(-8.0f * du * du);
                feat[fo + 4 + i] = __expf(-8.0f * dvv * dvv);
            }
        }
        // r one-blob (52..55)
        {
            const float x = 1.0f - __expf(-rv);
#pragma unroll
            for (int i = 0; i < 4; ++i) {
                const float cc = (i + 0.5f) * 0.25f;
                const float dx = x - cc;
                feat[52 + i] = __expf(-8.0f * dx * dx);
            }
        }
        feat[56] = av[0]; feat[57] = av[1]; feat[58] = av[2];
        feat[59] = bv[0]; feat[60] = bv[1]; feat[61] = bv[2];
        feat[62] = 1.0f;  feat[63] = 1.0f;

        // stash alpha+beta for the epilogue
        f32x4 abv;
        abv[0] = av[0] + bv[0]; abv[1] = av[1] + bv[1];
        abv[2] = av[2] + bv[2]; abv[3] = 0.0f;
        *(f32x4*)(abb + lane * 16) = abv;

        // write features to this sample's tile (tile = q, row = m), B-frag layout
        unsigned char* const tb = hb + q * 2048;
#pragma unroll
        for (int fc = 0; fc < 8; ++fc) {
            f16x8 v = pack8(&feat[fc * 8]);
            *(f16x8*)(tb + fc * 256 + m * 16) = v;
        }
    }
    // Wave-private tiles: LDS is in-order per wave, but the COMPILER must not
    // reorder the encode stores vs the layer-0 loads (distinct vector TBAA).
    LDS_FENCE();

    // ---- hidden layers 0..5 (weight-stationary, tiles inner) ----
    const float* const Ws[6] = {W0, W1, W2, W3, W4, W5};
#pragma unroll
    for (int layer = 0; layer < 6; ++layer) {
        const float* __restrict__ Wl = Ws[layer];
        f16x8 wf[2][4];
#pragma unroll
        for (int kt = 0; kt < 2; ++kt)
#pragma unroll
            for (int mt = 0; mt < 4; ++mt)
                wf[kt][mt] = load_wfrag(Wl, mt * 16 + m, kt * 32 + q * 8);

        for (int t = 0; t < TILES; ++t) {
            unsigned char* const tb = hb + t * 2048;
            const f16x8 bf0 = *(const f16x8*)(tb +        q * 256 + m * 16);
            const f16x8 bf1 = *(const f16x8*)(tb + 1024 + q * 256 + m * 16);
            f32x4 acc[4];
#pragma unroll
            for (int mt = 0; mt < 4; ++mt) {
                f32x4 z = {0.0f, 0.0f, 0.0f, 0.0f};
                z = MFMA16(wf[0][mt], bf0, z);
                z = MFMA16(wf[1][mt], bf1, z);
                acc[mt] = z;
            }
            LDS_FENCE();   // reads of this tile complete (in program order) before overwrite
            // ReLU + f16 pack + write back in B-frag layout:
            // lane holds h_next[f = mt*16 + q*4 + r][s = m], r=0..3 contiguous
#pragma unroll
            for (int mt = 0; mt < 4; ++mt) {
                const float r0 = fmaxf(acc[mt][0], 0.0f);
                const float r1 = fmaxf(acc[mt][1], 0.0f);
                const float r2 = fmaxf(acc[mt][2], 0.0f);
                const float r3 = fmaxf(acc[mt][3], 0.0f);
                const f16x2 lo = pkh(r0, r1);
                const f16x2 hi = pkh(r2, r3);
                f16x4 v;
                v[0] = lo[0]; v[1] = lo[1]; v[2] = hi[0]; v[3] = hi[1];
                *(f16x4*)(tb + (mt * 2 + (q >> 1)) * 256 + m * 16 + (q & 1) * 8) = v;
            }
            LDS_FENCE();   // writeback ordered before next layer's reads
        }
    }

    // ---- final layer (W6, 3 outputs) + scale by (alpha+beta) ----
    {
        const f16x8 w6f0 = *(const f16x8*)(w6b + lane * 16);
        const f16x8 w6f1 = *(const f16x8*)(w6b + (64 + lane) * 16);
        for (int t = 0; t < TILES; ++t) {
            unsigned char* const tb = hb + t * 2048;
            const f16x8 bf0 = *(const f16x8*)(tb +        q * 256 + m * 16);
            const f16x8 bf1 = *(const f16x8*)(tb + 1024 + q * 256 + m * 16);
            f32x4 z = {0.0f, 0.0f, 0.0f, 0.0f};
            z = MFMA16(w6f0, bf0, z);
            z = MFMA16(w6f1, bf1, z);
            const f32x4 abv = *(const f32x4*)(abb + (t * 16 + m) * 16);
            if (lane < 16) {
                // q==0: rows r=0..2 are the 3 output channels for sample col m
                const int s = wave_base + t * 16 + m;
                float* o = Out + s * 3;
                o[0] = z[0] * abv[0];
                o[1] = z[1] * abv[1];
                o[2] = z[2] * abv[2];
            }
        }
    }
}

extern "C" void kernel_launch(void* const* d_in, const int* in_sizes, int n_in,
                              void* d_out, int out_size, void* d_ws, size_t ws_size,
                              hipStream_t stream) {
    (void)n_in; (void)d_ws; (void)ws_size; (void)out_size;
    const float* P  = (const float*)d_in[0];
    const float* WI = (const float*)d_in[1];
    const float* NV = (const float*)d_in[2];
    const float* AL = (const float*)d_in[3];
    const float* BE = (const float*)d_in[4];
    const float* RR = (const float*)d_in[5];
    const float* W0 = (const float*)d_in[6];
    const float* W1 = (const float*)d_in[7];
    const float* W2 = (const float*)d_in[8];
    const float* W3 = (const float*)d_in[9];
    const float* W4 = (const float*)d_in[10];
    const float* W5 = (const float*)d_in[11];
    const float* W6 = (const float*)d_in[12];
    float* Out = (float*)d_out;

    const int Bn = in_sizes[0] / 3;     // 1,048,576
    const int grid = Bn / SPB;          // 8192 blocks of 128 threads

    hipLaunchKernelGGL(nrc_mlp_kernel, dim3(grid), dim3(BLOCK), 0, stream,
                       P, WI, NV, AL, BE, RR, W0, W1, W2, W3, W4, W5, W6, Out);
}

// Round 6
// 171.107 us; speedup vs baseline: 1.6729x; 1.6729x over previous
//
#include <hip/hip_runtime.h>

// NRC fused encode + 7-layer W=64 MLP, f16 MFMA (16x16x32), fp32 accumulate.
// Fragment maps (gfx950 16x16x32 f16, verified):
//   A[m=lane&15][k=(lane>>4)*8+j]   (A = weight rows, M = out features)
//   B[k=(lane>>4)*8+j][n=lane&15]   (B = h^T, N = samples)
//   D[row=(lane>>4)*4+r][col=lane&15]
// h in LDS in B-frag-native chunks: chunk fc holds features fc*8..fc*8+7
// for 16 samples, 16B per (chunk,row).
//
// R6: R5's d_ws overflow fix. R5 wrote 51200B of packed weights into d_ws
// without checking ws_size -> OOB writes corrupted adjacent allocations
// (pristine input copies), seen as post-timing divergence with consistent
// replays. Now: packed path only if ws_size >= 51200; else in-kernel f32->f16
// weight conversion (same MLP body either way — R5's body passed first-check).

typedef _Float16 f16;
typedef f16 f16x2 __attribute__((ext_vector_type(2)));
typedef f16 f16x4 __attribute__((ext_vector_type(4)));
typedef f16 f16x8 __attribute__((ext_vector_type(8)));
typedef float f32x4 __attribute__((ext_vector_type(4)));

#define MFMA16(A, B, C) __builtin_amdgcn_mfma_f32_16x16x32_f16(A, B, C, 0, 0, 0)
#define LDS_FENCE() __asm__ volatile("" ::: "memory")

static constexpr int TILES = 4;                  // 16-sample tiles per wave
static constexpr int WAVES = 2;                  // waves per block
static constexpr int BLOCK = WAVES * 64;         // 128 threads
static constexpr int SPB   = WAVES * TILES * 16; // 128 samples per block

// d_ws weight pack: 50 frag-units (48 hidden + 2 for W6), each 64 lanes x 16B.
// unit u (0..47): layer=u>>3, frag=u&7 (frag = kt*4+mt). units 48,49: W6 kt=0,1.
static constexpr int    WUNITS   = 50;
static constexpr size_t WS_BYTES = (size_t)WUNITS * 64 * 16;   // 51200

__device__ __forceinline__ f16x2 pkh(float a, float b) {
    return __builtin_bit_cast(f16x2, __builtin_amdgcn_cvt_pkrtz(a, b));
}

__device__ __forceinline__ f16x8 pack8(const float* f) {
    f16x2 a = pkh(f[0], f[1]);
    f16x2 b = pkh(f[2], f[3]);
    f16x2 c = pkh(f[4], f[5]);
    f16x2 d = pkh(f[6], f[7]);
    f16x8 v;
    v[0] = a[0]; v[1] = a[1]; v[2] = b[0]; v[3] = b[1];
    v[4] = c[0]; v[5] = c[1]; v[6] = d[0]; v[7] = d[1];
    return v;
}

__device__ __forceinline__ f16x8 load_wfrag(const float* __restrict__ Wl, int row, int k0) {
    const f32x4 lo = *(const f32x4*)(Wl + row * 64 + k0);
    const f32x4 hi = *(const f32x4*)(Wl + row * 64 + k0 + 4);
    float t[8] = {lo[0], lo[1], lo[2], lo[3], hi[0], hi[1], hi[2], hi[3]};
    return pack8(t);
}

// atan2(y,x) / (2*pi)  in (-0.5, 0.5]
__device__ __forceinline__ float fast_atan2_rev(float y, float x) {
    const float ax = __builtin_fabsf(x), ay = __builtin_fabsf(y);
    const float mx = fmaxf(ax, ay), mn = fminf(ax, ay);
    const float a = mn * __builtin_amdgcn_rcpf(fmaxf(mx, 1e-30f));
    const float s = a * a;
    float r = a * (0.99997726f + s * (-0.33262347f + s * (0.19354346f +
              s * (-0.11643287f + s * (0.05265332f - s * 0.01172120f)))));
    if (ay > ax) r = 1.5707963268f - r;
    if (x < 0.0f) r = 3.1415926536f - r;
    r = (y < 0.0f) ? -r : r;
    return r * 0.15915494309189535f;
}

// acos(x), |err| <= 6.8e-5 rad
__device__ __forceinline__ float fast_acos(float x) {
    const float ax = __builtin_fabsf(x);
    const float t = __builtin_amdgcn_sqrtf(1.0f - ax);
    const float p = t * (1.5707288f + ax * (-0.2121144f +
                    ax * (0.0742610f - ax * 0.0187293f)));
    return (x < 0.0f) ? (3.1415926536f - p) : p;
}

__global__ __launch_bounds__(256, 1) void pack_weights_kernel(
    const float* __restrict__ W0, const float* __restrict__ W1,
    const float* __restrict__ W2, const float* __restrict__ W3,
    const float* __restrict__ W4, const float* __restrict__ W5,
    const float* __restrict__ W6, f16* __restrict__ ws)
{
    const int u = (int)blockIdx.x * 256 + threadIdx.x;   // one thread per (unit,lane)
    if (u >= WUNITS * 64) return;
    const int lane = u & 63;
    const int unit = u >> 6;
    const int q = lane >> 4, m = lane & 15;
    f16x8 v;
    if (unit < 48) {
        const int l = unit >> 3, frag = unit & 7;
        const int kt = frag >> 2, mt = frag & 3;
        const float* Ws[6] = {W0, W1, W2, W3, W4, W5};
        const float* __restrict__ Wl = Ws[l];
        const int row = mt * 16 + m, col0 = kt * 32 + q * 8;
#pragma unroll
        for (int j = 0; j < 8; ++j) v[j] = (f16)Wl[row * 64 + col0 + j];
    } else {
        const int kt = unit - 48;
        const int col0 = kt * 32 + q * 8;
#pragma unroll
        for (int j = 0; j < 8; ++j)
            v[j] = (m < 3) ? (f16)W6[m * 64 + col0 + j] : (f16)0.0f;
    }
    *(f16x8*)(ws + unit * 512 + lane * 8) = v;
}

template<int PACKED>
__global__ __launch_bounds__(BLOCK, 3) void nrc_mlp_kernel(
    const float* __restrict__ P,  const float* __restrict__ WI,
    const float* __restrict__ NV, const float* __restrict__ AL,
    const float* __restrict__ BE, const float* __restrict__ RR,
    const f16*   __restrict__ ws,
    const float* __restrict__ W0, const float* __restrict__ W1,
    const float* __restrict__ W2, const float* __restrict__ W3,
    const float* __restrict__ W4, const float* __restrict__ W5,
    const float* __restrict__ W6, float* __restrict__ Out)
{
    // LDS: h tiles | ab(alpha+beta) -> 18432 B total
    __shared__ __attribute__((aligned(16)))
        unsigned char smem[WAVES * TILES * 2048 + WAVES * TILES * 16 * 16];

    const int tid  = threadIdx.x;
    const int lane = tid & 63;
    const int w    = tid >> 6;
    const int q    = lane >> 4;
    const int m    = lane & 15;

    unsigned char* const hb  = smem + w * (TILES * 2048);
    unsigned char* const abb = smem + WAVES * TILES * 2048 + w * (TILES * 16 * 16);

    const int wave_base = (int)blockIdx.x * SPB + w * (TILES * 16);

    // ---- encode: 64 samples, one per lane ----
    {
        const int s = wave_base + lane;

        float pv[3], wv[3], nv[3], av[3], bv[3];
#pragma unroll
        for (int d = 0; d < 3; ++d) {
            pv[d] = P [s * 3 + d];
            wv[d] = WI[s * 3 + d];
            nv[d] = NV[s * 3 + d];
            av[d] = AL[s * 3 + d];
            bv[d] = BE[s * 3 + d];
        }
        const float rv = RR[s];

        float feat[64];
        // sin(pi*p*2^k) = v_sin(fract(p*2^(k-1))) [revolutions]
#pragma unroll
        for (int d = 0; d < 3; ++d) {
#pragma unroll
            for (int k = 0; k < 6; ++k) {
                const float rev = pv[d] * (0.5f * (float)(1 << k));
                const float fr  = __builtin_amdgcn_fractf(rev);
                feat[d * 12 + k]     = __builtin_amdgcn_sinf(fr);
                feat[d * 12 + 6 + k] = __builtin_amdgcn_cosf(fr);
            }
        }
#pragma unroll
        for (int which = 0; which < 2; ++which) {
            const float* dv = (which == 0) ? wv : nv;
            const int fo = 36 + which * 8;
            const float nr = __builtin_amdgcn_sqrtf(dv[0]*dv[0] + dv[1]*dv[1] + dv[2]*dv[2]) + 1e-8f;
            const float u  = fast_atan2_rev(dv[1], dv[0]) + 0.5f;
            float zc = dv[2] * __builtin_amdgcn_rcpf(nr);
            zc = fminf(fmaxf(zc, -1.0f + 1e-6f), 1.0f - 1e-6f);
            const float vv = fast_acos(zc) * 0.3183098861837907f;
#pragma unroll
            for (int i = 0; i < 4; ++i) {
                const float cc = (i + 0.5f) * 0.25f;
                const float du = u - cc, dvv = vv - cc;
                feat[fo + i]     = __expf(-8.0f * du * du);
                feat[fo + 4 + i] = __expf(-8.0f * dvv * dvv);
            }
        }
        {
            const float x = 1.0f - __expf(-rv);
#pragma unroll
            for (int i = 0; i < 4; ++i) {
                const float cc = (i + 0.5f) * 0.25f;
                const float dx = x - cc;
                feat[52 + i] = __expf(-8.0f * dx * dx);
            }
        }
        feat[56] = av[0]; feat[57] = av[1]; feat[58] = av[2];
        feat[59] = bv[0]; feat[60] = bv[1]; feat[61] = bv[2];
        feat[62] = 1.0f;  feat[63] = 1.0f;

        f32x4 abv;
        abv[0] = av[0] + bv[0]; abv[1] = av[1] + bv[1];
        abv[2] = av[2] + bv[2]; abv[3] = 0.0f;
        *(f32x4*)(abb + lane * 16) = abv;

        // write features to tile q, row m (B-frag layout)
        unsigned char* const tb = hb + q * 2048;
#pragma unroll
        for (int fc = 0; fc < 8; ++fc) {
            f16x8 v = pack8(&feat[fc * 8]);
            *(f16x8*)(tb + fc * 256 + m * 16) = v;
        }
    }
    LDS_FENCE();   // encode writes ordered before layer-0 reads (cross-lane, same wave)

    const f16* const wbase = ws + (size_t)lane * 8;
    const float* const Ws[6] = {W0, W1, W2, W3, W4, W5};

    // ---- hidden layers 0..5 ----
#pragma unroll
    for (int layer = 0; layer < 6; ++layer) {
        // weight frags (frag = kt*4+mt)
        f16x8 wf[8];
        if (PACKED) {
#pragma unroll
            for (int f = 0; f < 8; ++f)
                wf[f] = *(const f16x8*)(wbase + (layer * 8 + f) * 512);
        } else {
            const float* __restrict__ Wl = Ws[layer];
#pragma unroll
            for (int kt = 0; kt < 2; ++kt)
#pragma unroll
                for (int mt = 0; mt < 4; ++mt)
                    wf[kt * 4 + mt] = load_wfrag(Wl, mt * 16 + m, kt * 32 + q * 8);
        }

        // batched LDS reads: all tiles' B-frags in flight together
        f16x8 bf[TILES][2];
#pragma unroll
        for (int t = 0; t < TILES; ++t) {
            unsigned char* const tb = hb + t * 2048;
            bf[t][0] = *(const f16x8*)(tb +        q * 256 + m * 16);
            bf[t][1] = *(const f16x8*)(tb + 1024 + q * 256 + m * 16);
        }
        LDS_FENCE();   // read batch completes (program order) before write batch

#pragma unroll
        for (int t = 0; t < TILES; ++t) {
            unsigned char* const tb = hb + t * 2048;
            f32x4 acc[4];
#pragma unroll
            for (int mt = 0; mt < 4; ++mt) {
                f32x4 z = {0.0f, 0.0f, 0.0f, 0.0f};
                z = MFMA16(wf[mt],     bf[t][0], z);
                z = MFMA16(wf[4 + mt], bf[t][1], z);
                acc[mt] = z;
            }
            // ReLU + pack + write back in B-frag layout
#pragma unroll
            for (int mt = 0; mt < 4; ++mt) {
                const float r0 = fmaxf(acc[mt][0], 0.0f);
                const float r1 = fmaxf(acc[mt][1], 0.0f);
                const float r2 = fmaxf(acc[mt][2], 0.0f);
                const float r3 = fmaxf(acc[mt][3], 0.0f);
                const f16x2 lo = pkh(r0, r1);
                const f16x2 hi = pkh(r2, r3);
                f16x4 v;
                v[0] = lo[0]; v[1] = lo[1]; v[2] = hi[0]; v[3] = hi[1];
                *(f16x4*)(tb + (mt * 2 + (q >> 1)) * 256 + m * 16 + (q & 1) * 8) = v;
            }
        }
        LDS_FENCE();   // layer writes ordered before next layer's reads
    }

    // ---- final layer (W6, 3 rows padded to 16) + scale by (alpha+beta) ----
    {
        f16x8 w6f0, w6f1;
        if (PACKED) {
            w6f0 = *(const f16x8*)(wbase + 48 * 512);
            w6f1 = *(const f16x8*)(wbase + 49 * 512);
        } else {
            float t0[8], t1[8];
#pragma unroll
            for (int j = 0; j < 8; ++j) {
                t0[j] = (m < 3) ? W6[m * 64 +      q * 8 + j] : 0.0f;
                t1[j] = (m < 3) ? W6[m * 64 + 32 + q * 8 + j] : 0.0f;
            }
            w6f0 = pack8(t0);
            w6f1 = pack8(t1);
        }
#pragma unroll
        for (int t = 0; t < TILES; ++t) {
            unsigned char* const tb = hb + t * 2048;
            const f16x8 bf0 = *(const f16x8*)(tb +        q * 256 + m * 16);
            const f16x8 bf1 = *(const f16x8*)(tb + 1024 + q * 256 + m * 16);
            f32x4 z = {0.0f, 0.0f, 0.0f, 0.0f};
            z = MFMA16(w6f0, bf0, z);
            z = MFMA16(w6f1, bf1, z);
            const f32x4 abv = *(const f32x4*)(abb + (t * 16 + m) * 16);
            if (lane < 16) {
                const int s = wave_base + t * 16 + m;
                float* o = Out + s * 3;
                o[0] = z[0] * abv[0];
                o[1] = z[1] * abv[1];
                o[2] = z[2] * abv[2];
            }
        }
    }
}

extern "C" void kernel_launch(void* const* d_in, const int* in_sizes, int n_in,
                              void* d_out, int out_size, void* d_ws, size_t ws_size,
                              hipStream_t stream) {
    (void)n_in; (void)out_size;
    const float* P  = (const float*)d_in[0];
    const float* WI = (const float*)d_in[1];
    const float* NV = (const float*)d_in[2];
    const float* AL = (const float*)d_in[3];
    const float* BE = (const float*)d_in[4];
    const float* RR = (const float*)d_in[5];
    const float* W0 = (const float*)d_in[6];
    const float* W1 = (const float*)d_in[7];
    const float* W2 = (const float*)d_in[8];
    const float* W3 = (const float*)d_in[9];
    const float* W4 = (const float*)d_in[10];
    const float* W5 = (const float*)d_in[11];
    const float* W6 = (const float*)d_in[12];
    f16*   ws  = (f16*)d_ws;
    float* Out = (float*)d_out;

    const int Bn = in_sizes[0] / 3;     // 1,048,576
    const int grid = Bn / SPB;          // 8192 blocks of 128 threads

    // ws_size is fixed for the session -> same path every call (graph-safe).
    if (ws_size >= WS_BYTES) {
        hipLaunchKernelGGL(pack_weights_kernel, dim3((WUNITS * 64 + 255) / 256),
                           dim3(256), 0, stream, W0, W1, W2, W3, W4, W5, W6, ws);
        hipLaunchKernelGGL((nrc_mlp_kernel<1>), dim3(grid), dim3(BLOCK), 0, stream,
                           P, WI, NV, AL, BE, RR, ws,
                           W0, W1, W2, W3, W4, W5, W6, Out);
    } else {
        hipLaunchKernelGGL((nrc_mlp_kernel<0>), dim3(grid), dim3(BLOCK), 0, stream,
                           P, WI, NV, AL, BE, RR, ws,
                           W0, W1, W2, W3, W4, W5, W6, Out);
    }
}

// Round 7
// 170.078 us; speedup vs baseline: 1.6831x; 1.0061x over previous
//
#include <hip/hip_runtime.h>

// NRC fused encode + 7-layer W=64 MLP. R7: register-resident hidden state.
//
// Legacy MFMA shape 16x16x16 f16 (gfx950 carries it forward):
//   A[i=lane&15][k=(lane>>4)*4+j]  (4 f16/lane)
//   B[k=(lane>>4)*4+j][n=lane&15]  (4 f16/lane)
//   D[row=(lane>>4)*4+r][col=lane&15] (4 f32/lane)
// KEY IDENTITY: B's k-subindex (q*4+j) == D's row-subindex (q*4+r), n == col.
// So relu(D_block_mt) packed to f16x4 IS the next layer's B-frag for feature
// block kb=mt — the whole MLP chains through registers with ZERO LDS traffic
// between layers. LDS used once: encode -> B-frag distribution (swizzled).
// Layer: acc[mt] = sum_kb MFMA16(Wfrag[mt][kb], h[kb], acc[mt]) (16 MFMAs/tile,
// same MACs as 8x K=32).
//
// Block = 1 wave (64 threads), 4 tiles x 16 samples, no barriers at all.
// LDS 9216 B; __launch_bounds__(64,4) -> 16 waves/CU.

typedef _Float16 f16;
typedef f16 f16x2 __attribute__((ext_vector_type(2)));
typedef f16 f16x4 __attribute__((ext_vector_type(4)));
typedef f16 f16x8 __attribute__((ext_vector_type(8)));
typedef float f32x4 __attribute__((ext_vector_type(4)));

#define MFMA16(A, B, C) __builtin_amdgcn_mfma_f32_16x16x16f16(A, B, C, 0, 0, 0)
#define LDS_FENCE() __asm__ volatile("" ::: "memory")

static constexpr int TILES = 4;       // 16-sample tiles per wave
static constexpr int BLOCK = 64;      // 1 wave per block
static constexpr int SPB   = 64;      // samples per block

// d_ws pack: 50 units x 64 lanes x 16B = 51200 B.
// unit u<48: layer=u>>3, rem=u&7, mt=rem>>1, kbh=rem&1; lane(q,m) holds 8 f16:
//   e=0..7: kb=kbh*2+(e>>2), j=e&3 -> W[mt*16+m][kb*16+q*4+j]
// units 48,49: W6 (rows m<3 else 0), kbh=u-48, same e-mapping with mt=0.
static constexpr int    WUNITS   = 50;
static constexpr size_t WS_BYTES = (size_t)WUNITS * 64 * 16;   // 51200

__device__ __forceinline__ f16x2 pkh(float a, float b) {
    return __builtin_bit_cast(f16x2, __builtin_amdgcn_cvt_pkrtz(a, b));
}

__device__ __forceinline__ f16x8 pack8(const float* f) {
    f16x2 a = pkh(f[0], f[1]);
    f16x2 b = pkh(f[2], f[3]);
    f16x2 c = pkh(f[4], f[5]);
    f16x2 d = pkh(f[6], f[7]);
    f16x8 v;
    v[0] = a[0]; v[1] = a[1]; v[2] = b[0]; v[3] = b[1];
    v[4] = c[0]; v[5] = c[1]; v[6] = d[0]; v[7] = d[1];
    return v;
}

__device__ __forceinline__ f16x4 pack4(f32x4 v) {
    f16x2 a = pkh(v[0], v[1]);
    f16x2 b = pkh(v[2], v[3]);
    f16x4 r;
    r[0] = a[0]; r[1] = a[1]; r[2] = b[0]; r[3] = b[1];
    return r;
}

// atan2(y,x) / (2*pi)
__device__ __forceinline__ float fast_atan2_rev(float y, float x) {
    const float ax = __builtin_fabsf(x), ay = __builtin_fabsf(y);
    const float mx = fmaxf(ax, ay), mn = fminf(ax, ay);
    const float a = mn * __builtin_amdgcn_rcpf(fmaxf(mx, 1e-30f));
    const float s = a * a;
    float r = a * (0.99997726f + s * (-0.33262347f + s * (0.19354346f +
              s * (-0.11643287f + s * (0.05265332f - s * 0.01172120f)))));
    if (ay > ax) r = 1.5707963268f - r;
    if (x < 0.0f) r = 3.1415926536f - r;
    r = (y < 0.0f) ? -r : r;
    return r * 0.15915494309189535f;
}

// acos(x), |err| <= 6.8e-5 rad
__device__ __forceinline__ float fast_acos(float x) {
    const float ax = __builtin_fabsf(x);
    const float t = __builtin_amdgcn_sqrtf(1.0f - ax);
    const float p = t * (1.5707288f + ax * (-0.2121144f +
                    ax * (0.0742610f - ax * 0.0187293f)));
    return (x < 0.0f) ? (3.1415926536f - p) : p;
}

__global__ __launch_bounds__(256, 1) void pack_weights_kernel(
    const float* __restrict__ W0, const float* __restrict__ W1,
    const float* __restrict__ W2, const float* __restrict__ W3,
    const float* __restrict__ W4, const float* __restrict__ W5,
    const float* __restrict__ W6, f16* __restrict__ ws)
{
    const int u = (int)blockIdx.x * 256 + threadIdx.x;
    if (u >= WUNITS * 64) return;
    const int lane = u & 63;
    const int unit = u >> 6;
    const int q = lane >> 4, m = lane & 15;
    f16x8 v;
    if (unit < 48) {
        const int l = unit >> 3, rem = unit & 7;
        const int mt = rem >> 1, kbh = rem & 1;
        const float* Ws[6] = {W0, W1, W2, W3, W4, W5};
        const float* __restrict__ Wl = Ws[l];
#pragma unroll
        for (int e = 0; e < 8; ++e) {
            const int kb = kbh * 2 + (e >> 2), j = e & 3;
            v[e] = (f16)Wl[(mt * 16 + m) * 64 + kb * 16 + q * 4 + j];
        }
    } else {
        const int kbh = unit - 48;
#pragma unroll
        for (int e = 0; e < 8; ++e) {
            const int kb = kbh * 2 + (e >> 2), j = e & 3;
            v[e] = (m < 3) ? (f16)W6[m * 64 + kb * 16 + q * 4 + j] : (f16)0.0f;
        }
    }
    *(f16x8*)(ws + unit * 512 + lane * 8) = v;
}

__device__ __forceinline__ f16x4 lo4(f16x8 v) {
    return __builtin_shufflevector(v, v, 0, 1, 2, 3);
}
__device__ __forceinline__ f16x4 hi4(f16x8 v) {
    return __builtin_shufflevector(v, v, 4, 5, 6, 7);
}

template<int PACKED>
__global__ __launch_bounds__(BLOCK, 4) void nrc_mlp_kernel(
    const float* __restrict__ P,  const float* __restrict__ WI,
    const float* __restrict__ NV, const float* __restrict__ AL,
    const float* __restrict__ BE, const float* __restrict__ RR,
    const f16*   __restrict__ ws,
    const float* __restrict__ W0, const float* __restrict__ W1,
    const float* __restrict__ W2, const float* __restrict__ W3,
    const float* __restrict__ W4, const float* __restrict__ W5,
    const float* __restrict__ W6, float* __restrict__ Out)
{
    // LDS: 4 tiles x 2048 (f16-pair slots, swizzled) + 1024 ab = 9216 B
    __shared__ __attribute__((aligned(16))) unsigned char smem[TILES * 2048 + TILES * 16 * 16];

    const int lane = threadIdx.x & 63;
    const int q    = lane >> 4;
    const int m    = lane & 15;
    unsigned char* const hb  = smem;
    unsigned char* const abb = smem + TILES * 2048;

    const int wave_base = (int)blockIdx.x * SPB;

    // ---- encode: one sample per lane ----
    {
        const int s = wave_base + lane;

        float pv[3], wv[3], nv[3], av[3], bv[3];
#pragma unroll
        for (int d = 0; d < 3; ++d) {
            pv[d] = P [s * 3 + d];
            wv[d] = WI[s * 3 + d];
            nv[d] = NV[s * 3 + d];
            av[d] = AL[s * 3 + d];
            bv[d] = BE[s * 3 + d];
        }
        const float rv = RR[s];

        float feat[64];
#pragma unroll
        for (int d = 0; d < 3; ++d) {
#pragma unroll
            for (int k = 0; k < 6; ++k) {
                const float rev = pv[d] * (0.5f * (float)(1 << k));
                const float fr  = __builtin_amdgcn_fractf(rev);
                feat[d * 12 + k]     = __builtin_amdgcn_sinf(fr);
                feat[d * 12 + 6 + k] = __builtin_amdgcn_cosf(fr);
            }
        }
#pragma unroll
        for (int which = 0; which < 2; ++which) {
            const float* dv = (which == 0) ? wv : nv;
            const int fo = 36 + which * 8;
            const float nr = __builtin_amdgcn_sqrtf(dv[0]*dv[0] + dv[1]*dv[1] + dv[2]*dv[2]) + 1e-8f;
            const float u  = fast_atan2_rev(dv[1], dv[0]) + 0.5f;
            float zc = dv[2] * __builtin_amdgcn_rcpf(nr);
            zc = fminf(fmaxf(zc, -1.0f + 1e-6f), 1.0f - 1e-6f);
            const float vv = fast_acos(zc) * 0.3183098861837907f;
#pragma unroll
            for (int i = 0; i < 4; ++i) {
                const float cc = (i + 0.5f) * 0.25f;
                const float du = u - cc, dvv = vv - cc;
                feat[fo + i]     = __expf(-8.0f * du * du);
                feat[fo + 4 + i] = __expf(-8.0f * dvv * dvv);
            }
        }
        {
            const float x = 1.0f - __expf(-rv);
#pragma unroll
            for (int i = 0; i < 4; ++i) {
                const float cc = (i + 0.5f) * 0.25f;
                const float dx = x - cc;
                feat[52 + i] = __expf(-8.0f * dx * dx);
            }
        }
        feat[56] = av[0]; feat[57] = av[1]; feat[58] = av[2];
        feat[59] = bv[0]; feat[60] = bv[1]; feat[61] = bv[2];
        feat[62] = 1.0f;  feat[63] = 1.0f;

        f32x4 abv;
        abv[0] = av[0] + bv[0]; abv[1] = av[1] + bv[1];
        abv[2] = av[2] + bv[2]; abv[3] = 0.0f;
        *(f32x4*)(abb + lane * 16) = abv;

        // features -> LDS, pair-slot layout [tile=lane>>4][m][slot], slot
        // swizzled by +4m so reads spread banks; groups of 4 slots stay
        // contiguous (wrap only at group boundary).
        const int te = lane >> 4, me = lane & 15;
        unsigned char* const tb = hb + te * 2048 + me * 128;
#pragma unroll
        for (int g = 0; g < 8; ++g) {
            const int slot0 = (4 * g + 4 * me) & 31;
            *(f16x8*)(tb + slot0 * 4) = pack8(&feat[g * 8]);
        }
    }
    LDS_FENCE();   // encode writes ordered before frag reads (same wave)

    // ---- load B-frags for all tiles (the ONLY LDS->frag pass) ----
    // lane(q,m), tile t, block kb: pairs p=kb*8+q*2,+1 -> slots (p+4m)&31,+1
    f16x4 bf[TILES][4];
#pragma unroll
    for (int t = 0; t < TILES; ++t) {
#pragma unroll
        for (int kb = 0; kb < 4; ++kb) {
            const int s0 = (kb * 8 + q * 2 + 4 * m) & 31;
            bf[t][kb] = *(const f16x4*)(hb + t * 2048 + m * 128 + s0 * 4);
        }
    }

    const f16* const wbase = ws + (size_t)lane * 8;
    const float* const Ws[6] = {W0, W1, W2, W3, W4, W5};
    const f16x4 zero4 = {(f16)0.0f, (f16)0.0f, (f16)0.0f, (f16)0.0f};

    // ---- hidden layers: h chains through registers, no LDS ----
#pragma unroll
    for (int layer = 0; layer < 6; ++layer) {
        f16x4 wa[4][4];   // [mt][kb]
        if (PACKED) {
#pragma unroll
            for (int i = 0; i < 8; ++i) {
                const f16x8 v = *(const f16x8*)(wbase + (layer * 8 + i) * 512);
                const int mt = i >> 1, kbh = i & 1;
                wa[mt][kbh * 2]     = lo4(v);
                wa[mt][kbh * 2 + 1] = hi4(v);
            }
        } else {
            const float* __restrict__ Wl = Ws[layer];
#pragma unroll
            for (int mt = 0; mt < 4; ++mt)
#pragma unroll
                for (int kb = 0; kb < 4; ++kb)
                    wa[mt][kb] = pack4(*(const f32x4*)(Wl + (mt * 16 + m) * 64 + kb * 16 + q * 4));
        }

#pragma unroll
        for (int t = 0; t < TILES; ++t) {
            f32x4 acc[4];
#pragma unroll
            for (int mt = 0; mt < 4; ++mt) {
                f32x4 z = {0.0f, 0.0f, 0.0f, 0.0f};
#pragma unroll
                for (int kb = 0; kb < 4; ++kb)
                    z = MFMA16(wa[mt][kb], bf[t][kb], z);
                acc[mt] = z;
            }
            // relu(D_mt) packed = next layer's B-frag for kb=mt (in-lane!)
#pragma unroll
            for (int mt = 0; mt < 4; ++mt)
                bf[t][mt] = __builtin_elementwise_max(pack4(acc[mt]), zero4);
        }
    }

    // ---- final layer (W6) + scale by (alpha+beta) ----
    {
        f16x4 w6a[4];
        if (PACKED) {
            const f16x8 v0 = *(const f16x8*)(wbase + 48 * 512);
            const f16x8 v1 = *(const f16x8*)(wbase + 49 * 512);
            w6a[0] = lo4(v0); w6a[1] = hi4(v0);
            w6a[2] = lo4(v1); w6a[3] = hi4(v1);
        } else {
#pragma unroll
            for (int kb = 0; kb < 4; ++kb) {
                f32x4 t4 = {0.0f, 0.0f, 0.0f, 0.0f};
                if (m < 3) t4 = *(const f32x4*)(W6 + m * 64 + kb * 16 + q * 4);
                w6a[kb] = pack4(t4);
            }
        }
#pragma unroll
        for (int t = 0; t < TILES; ++t) {
            f32x4 z = {0.0f, 0.0f, 0.0f, 0.0f};
#pragma unroll
            for (int kb = 0; kb < 4; ++kb)
                z = MFMA16(w6a[kb], bf[t][kb], z);
            const f32x4 abv = *(const f32x4*)(abb + (t * 16 + m) * 16);
            if (lane < 16) {   // q==0: rows r=0..2 = output channels, col m
                const int s = wave_base + t * 16 + m;
                float* o = Out + s * 3;
                o[0] = z[0] * abv[0];
                o[1] = z[1] * abv[1];
                o[2] = z[2] * abv[2];
            }
        }
    }
}

extern "C" void kernel_launch(void* const* d_in, const int* in_sizes, int n_in,
                              void* d_out, int out_size, void* d_ws, size_t ws_size,
                              hipStream_t stream) {
    (void)n_in; (void)out_size;
    const float* P  = (const float*)d_in[0];
    const float* WI = (const float*)d_in[1];
    const float* NV = (const float*)d_in[2];
    const float* AL = (const float*)d_in[3];
    const float* BE = (const float*)d_in[4];
    const float* RR = (const float*)d_in[5];
    const float* W0 = (const float*)d_in[6];
    const float* W1 = (const float*)d_in[7];
    const float* W2 = (const float*)d_in[8];
    const float* W3 = (const float*)d_in[9];
    const float* W4 = (const float*)d_in[10];
    const float* W5 = (const float*)d_in[11];
    const float* W6 = (const float*)d_in[12];
    f16*   ws  = (f16*)d_ws;
    float* Out = (float*)d_out;

    const int Bn = in_sizes[0] / 3;     // 1,048,576
    const int grid = Bn / SPB;          // 16384 blocks of 64 threads

    // ws_size fixed per session -> same path every call (graph-safe).
    if (ws_size >= WS_BYTES) {
        hipLaunchKernelGGL(pack_weights_kernel, dim3((WUNITS * 64 + 255) / 256),
                           dim3(256), 0, stream, W0, W1, W2, W3, W4, W5, W6, ws);
        hipLaunchKernelGGL((nrc_mlp_kernel<1>), dim3(grid), dim3(BLOCK), 0, stream,
                           P, WI, NV, AL, BE, RR, ws,
                           W0, W1, W2, W3, W4, W5, W6, Out);
    } else {
        hipLaunchKernelGGL((nrc_mlp_kernel<0>), dim3(grid), dim3(BLOCK), 0, stream,
                           P, WI, NV, AL, BE, RR, ws,
                           W0, W1, W2, W3, W4, W5, W6, Out);
    }
}

// Round 8
// 169.323 us; speedup vs baseline: 1.6906x; 1.0045x over previous
//
#include <hip/hip_runtime.h>

// NRC fused encode + 7-layer W=64 MLP. R8 = R7 (register-resident hidden
// state via 16x16x16 chaining identity) + register-pressure fix + encode diet.
//
// R7 post-mortem: VGPR_Count=64 with launch_bounds(64,4) — the allocator hit
// its 4-wave occupancy target by rematerializing/serializing (bf+wa+acc need
// ~80+ regs live), exposing VMEM/LDS latency per layer; waves ~80% stalled.
// R8: launch_bounds(64,3) -> 170-reg cap; encode trig by angle-doubling and
// one-blob exp ladder (fewer quarter-rate transcendentals).
//
// 16x16x16 f16 fragment maps:
//   A[i=lane&15][k=(lane>>4)*4+j], B[k=(lane>>4)*4+j][n=lane&15],
//   D[row=(lane>>4)*4+r][col=lane&15]
// Chaining identity: B's k-subindex == D's row-subindex, n == col, so
// relu(D_mt) packed to f16x4 IS next layer's B-frag for kb=mt, in-lane.

typedef _Float16 f16;
typedef f16 f16x2 __attribute__((ext_vector_type(2)));
typedef f16 f16x4 __attribute__((ext_vector_type(4)));
typedef f16 f16x8 __attribute__((ext_vector_type(8)));
typedef float f32x4 __attribute__((ext_vector_type(4)));

#define MFMA16(A, B, C) __builtin_amdgcn_mfma_f32_16x16x16f16(A, B, C, 0, 0, 0)
#define LDS_FENCE() __asm__ volatile("" ::: "memory")

static constexpr int TILES = 4;       // 16-sample tiles per wave
static constexpr int BLOCK = 64;      // 1 wave per block
static constexpr int SPB   = 64;      // samples per block

// d_ws pack (R7 layout): 50 units x 64 lanes x 16B = 51200 B.
// unit u<48: layer=u>>3, rem=u&7, mt=rem>>1, kbh=rem&1; lane(q,m) 8 f16:
//   e: kb=kbh*2+(e>>2), j=e&3 -> W[mt*16+m][kb*16+q*4+j]
// units 48,49: W6 (rows m<3 else 0), kbh=u-48.
static constexpr int    WUNITS   = 50;
static constexpr size_t WS_BYTES = (size_t)WUNITS * 64 * 16;   // 51200

__device__ __forceinline__ f16x2 pkh(float a, float b) {
    return __builtin_bit_cast(f16x2, __builtin_amdgcn_cvt_pkrtz(a, b));
}

__device__ __forceinline__ f16x8 pack8(const float* f) {
    f16x2 a = pkh(f[0], f[1]);
    f16x2 b = pkh(f[2], f[3]);
    f16x2 c = pkh(f[4], f[5]);
    f16x2 d = pkh(f[6], f[7]);
    f16x8 v;
    v[0] = a[0]; v[1] = a[1]; v[2] = b[0]; v[3] = b[1];
    v[4] = c[0]; v[5] = c[1]; v[6] = d[0]; v[7] = d[1];
    return v;
}

__device__ __forceinline__ f16x4 pack4(f32x4 v) {
    f16x2 a = pkh(v[0], v[1]);
    f16x2 b = pkh(v[2], v[3]);
    f16x4 r;
    r[0] = a[0]; r[1] = a[1]; r[2] = b[0]; r[3] = b[1];
    return r;
}

// atan2(y,x) / (2*pi)
__device__ __forceinline__ float fast_atan2_rev(float y, float x) {
    const float ax = __builtin_fabsf(x), ay = __builtin_fabsf(y);
    const float mx = fmaxf(ax, ay), mn = fminf(ax, ay);
    const float a = mn * __builtin_amdgcn_rcpf(fmaxf(mx, 1e-30f));
    const float s = a * a;
    float r = a * (0.99997726f + s * (-0.33262347f + s * (0.19354346f +
              s * (-0.11643287f + s * (0.05265332f - s * 0.01172120f)))));
    if (ay > ax) r = 1.5707963268f - r;
    if (x < 0.0f) r = 3.1415926536f - r;
    r = (y < 0.0f) ? -r : r;
    return r * 0.15915494309189535f;
}

// acos(x), |err| <= 6.8e-5 rad
__device__ __forceinline__ float fast_acos(float x) {
    const float ax = __builtin_fabsf(x);
    const float t = __builtin_amdgcn_sqrtf(1.0f - ax);
    const float p = t * (1.5707288f + ax * (-0.2121144f +
                    ax * (0.0742610f - ax * 0.0187293f)));
    return (x < 0.0f) ? (3.1415926536f - p) : p;
}

// one-blob set: out[i] = exp(-8(x-c_i)^2), c_i=(i+.5)/4, via exp ladder:
// E_{i+1} = E_i * R * S^{2i+1}, R=exp(4(x-c0)), S=exp(-0.5). 2 trans + 6 mul.
__device__ __forceinline__ void blob4(float x, float* out) {
    const float dx = x - 0.125f;
    const float E0 = __expf(-8.0f * dx * dx);
    const float R  = __expf(4.0f * dx);
    const float t1 = R * 0.60653066f;    // S^1
    const float t2 = R * 0.22313016f;    // S^3
    const float t3 = R * 0.082084999f;   // S^5
    out[0] = E0;
    out[1] = E0 * t1;
    out[2] = out[1] * t2;
    out[3] = out[2] * t3;
}

__global__ __launch_bounds__(256, 1) void pack_weights_kernel(
    const float* __restrict__ W0, const float* __restrict__ W1,
    const float* __restrict__ W2, const float* __restrict__ W3,
    const float* __restrict__ W4, const float* __restrict__ W5,
    const float* __restrict__ W6, f16* __restrict__ ws)
{
    const int u = (int)blockIdx.x * 256 + threadIdx.x;
    if (u >= WUNITS * 64) return;
    const int lane = u & 63;
    const int unit = u >> 6;
    const int q = lane >> 4, m = lane & 15;
    f16x8 v;
    if (unit < 48) {
        const int l = unit >> 3, rem = unit & 7;
        const int mt = rem >> 1, kbh = rem & 1;
        const float* Ws[6] = {W0, W1, W2, W3, W4, W5};
        const float* __restrict__ Wl = Ws[l];
#pragma unroll
        for (int e = 0; e < 8; ++e) {
            const int kb = kbh * 2 + (e >> 2), j = e & 3;
            v[e] = (f16)Wl[(mt * 16 + m) * 64 + kb * 16 + q * 4 + j];
        }
    } else {
        const int kbh = unit - 48;
#pragma unroll
        for (int e = 0; e < 8; ++e) {
            const int kb = kbh * 2 + (e >> 2), j = e & 3;
            v[e] = (m < 3) ? (f16)W6[m * 64 + kb * 16 + q * 4 + j] : (f16)0.0f;
        }
    }
    *(f16x8*)(ws + unit * 512 + lane * 8) = v;
}

__device__ __forceinline__ f16x4 lo4(f16x8 v) {
    return __builtin_shufflevector(v, v, 0, 1, 2, 3);
}
__device__ __forceinline__ f16x4 hi4(f16x8 v) {
    return __builtin_shufflevector(v, v, 4, 5, 6, 7);
}

template<int PACKED>
__global__ __launch_bounds__(BLOCK, 3) void nrc_mlp_kernel(
    const float* __restrict__ P,  const float* __restrict__ WI,
    const float* __restrict__ NV, const float* __restrict__ AL,
    const float* __restrict__ BE, const float* __restrict__ RR,
    const f16*   __restrict__ ws,
    const float* __restrict__ W0, const float* __restrict__ W1,
    const float* __restrict__ W2, const float* __restrict__ W3,
    const float* __restrict__ W4, const float* __restrict__ W5,
    const float* __restrict__ W6, float* __restrict__ Out)
{
    // LDS: 4 tiles x 2048 (f16-pair slots, swizzled) + 1024 ab = 9216 B
    __shared__ __attribute__((aligned(16))) unsigned char smem[TILES * 2048 + TILES * 16 * 16];

    const int lane = threadIdx.x & 63;
    const int q    = lane >> 4;
    const int m    = lane & 15;
    unsigned char* const hb  = smem;
    unsigned char* const abb = smem + TILES * 2048;

    const int wave_base = (int)blockIdx.x * SPB;

    // ---- encode: one sample per lane ----
    {
        const int s = wave_base + lane;

        float pv[3], wv[3], nv[3], av[3], bv[3];
#pragma unroll
        for (int d = 0; d < 3; ++d) {
            pv[d] = P [s * 3 + d];
            wv[d] = WI[s * 3 + d];
            nv[d] = NV[s * 3 + d];
            av[d] = AL[s * 3 + d];
            bv[d] = BE[s * 3 + d];
        }
        const float rv = RR[s];

        float feat[64];
        // freq embed: base sin/cos at pi*p (revolutions), then angle-doubling:
        // s' = 2sc, c' = 1 - 2s^2  (exact doubling, err ~2^k ulp)
#pragma unroll
        for (int d = 0; d < 3; ++d) {
            const float fr = __builtin_amdgcn_fractf(pv[d] * 0.5f);
            float sv = __builtin_amdgcn_sinf(fr);
            float cv = __builtin_amdgcn_cosf(fr);
            feat[d * 12 + 0] = sv;
            feat[d * 12 + 6] = cv;
#pragma unroll
            for (int k = 1; k < 6; ++k) {
                const float s2 = sv * sv;
                const float sc = sv * cv;
                cv = fmaf(-2.0f, s2, 1.0f);
                sv = sc + sc;
                feat[d * 12 + k]     = sv;
                feat[d * 12 + 6 + k] = cv;
            }
        }
#pragma unroll
        for (int which = 0; which < 2; ++which) {
            const float* dv = (which == 0) ? wv : nv;
            const int fo = 36 + which * 8;
            const float nr = __builtin_amdgcn_sqrtf(dv[0]*dv[0] + dv[1]*dv[1] + dv[2]*dv[2]) + 1e-8f;
            const float u  = fast_atan2_rev(dv[1], dv[0]) + 0.5f;
            float zc = dv[2] * __builtin_amdgcn_rcpf(nr);
            zc = fminf(fmaxf(zc, -1.0f + 1e-6f), 1.0f - 1e-6f);
            const float vv = fast_acos(zc) * 0.3183098861837907f;
            blob4(u,  &feat[fo]);
            blob4(vv, &feat[fo + 4]);
        }
        blob4(1.0f - __expf(-rv), &feat[52]);

        feat[56] = av[0]; feat[57] = av[1]; feat[58] = av[2];
        feat[59] = bv[0]; feat[60] = bv[1]; feat[61] = bv[2];
        feat[62] = 1.0f;  feat[63] = 1.0f;

        f32x4 abv;
        abv[0] = av[0] + bv[0]; abv[1] = av[1] + bv[1];
        abv[2] = av[2] + bv[2]; abv[3] = 0.0f;
        *(f32x4*)(abb + lane * 16) = abv;

        // features -> LDS, pair-slot layout [tile=lane>>4][m][slot], slot
        // swizzled by +4m; groups of 4 slots contiguous.
        const int te = lane >> 4, me = lane & 15;
        unsigned char* const tb = hb + te * 2048 + me * 128;
#pragma unroll
        for (int g = 0; g < 8; ++g) {
            const int slot0 = (4 * g + 4 * me) & 31;
            *(f16x8*)(tb + slot0 * 4) = pack8(&feat[g * 8]);
        }
    }
    LDS_FENCE();   // encode writes ordered before frag reads (same wave)

    // ---- load B-frags for all tiles (the ONLY LDS->frag pass) ----
    f16x4 bf[TILES][4];
#pragma unroll
    for (int t = 0; t < TILES; ++t) {
#pragma unroll
        for (int kb = 0; kb < 4; ++kb) {
            const int s0 = (kb * 8 + q * 2 + 4 * m) & 31;
            bf[t][kb] = *(const f16x4*)(hb + t * 2048 + m * 128 + s0 * 4);
        }
    }

    const f16* const wbase = ws + (size_t)lane * 8;
    const float* const Ws[6] = {W0, W1, W2, W3, W4, W5};
    const f16x4 zero4 = {(f16)0.0f, (f16)0.0f, (f16)0.0f, (f16)0.0f};

    // ---- hidden layers: h chains through registers, no LDS ----
#pragma unroll
    for (int layer = 0; layer < 6; ++layer) {
        f16x4 wa[4][4];   // [mt][kb]
        if (PACKED) {
#pragma unroll
            for (int i = 0; i < 8; ++i) {
                const f16x8 v = *(const f16x8*)(wbase + (layer * 8 + i) * 512);
                const int mt = i >> 1, kbh = i & 1;
                wa[mt][kbh * 2]     = lo4(v);
                wa[mt][kbh * 2 + 1] = hi4(v);
            }
        } else {
            const float* __restrict__ Wl = Ws[layer];
#pragma unroll
            for (int mt = 0; mt < 4; ++mt)
#pragma unroll
                for (int kb = 0; kb < 4; ++kb)
                    wa[mt][kb] = pack4(*(const f32x4*)(Wl + (mt * 16 + m) * 64 + kb * 16 + q * 4));
        }

#pragma unroll
        for (int t = 0; t < TILES; ++t) {
            f32x4 acc[4];
#pragma unroll
            for (int mt = 0; mt < 4; ++mt) {
                f32x4 z = {0.0f, 0.0f, 0.0f, 0.0f};
#pragma unroll
                for (int kb = 0; kb < 4; ++kb)
                    z = MFMA16(wa[mt][kb], bf[t][kb], z);
                acc[mt] = z;
            }
            // relu(D_mt) packed = next layer's B-frag for kb=mt (in-lane)
#pragma unroll
            for (int mt = 0; mt < 4; ++mt)
                bf[t][mt] = __builtin_elementwise_max(pack4(acc[mt]), zero4);
        }
    }

    // ---- final layer (W6) + scale by (alpha+beta) ----
    {
        f16x4 w6a[4];
        if (PACKED) {
            const f16x8 v0 = *(const f16x8*)(wbase + 48 * 512);
            const f16x8 v1 = *(const f16x8*)(wbase + 49 * 512);
            w6a[0] = lo4(v0); w6a[1] = hi4(v0);
            w6a[2] = lo4(v1); w6a[3] = hi4(v1);
        } else {
#pragma unroll
            for (int kb = 0; kb < 4; ++kb) {
                f32x4 t4 = {0.0f, 0.0f, 0.0f, 0.0f};
                if (m < 3) t4 = *(const f32x4*)(W6 + m * 64 + kb * 16 + q * 4);
                w6a[kb] = pack4(t4);
            }
        }
#pragma unroll
        for (int t = 0; t < TILES; ++t) {
            f32x4 z = {0.0f, 0.0f, 0.0f, 0.0f};
#pragma unroll
            for (int kb = 0; kb < 4; ++kb)
                z = MFMA16(w6a[kb], bf[t][kb], z);
            const f32x4 abv = *(const f32x4*)(abb + (t * 16 + m) * 16);
            if (lane < 16) {   // q==0: rows r=0..2 = output channels, col m
                const int s = wave_base + t * 16 + m;
                float* o = Out + s * 3;
                o[0] = z[0] * abv[0];
                o[1] = z[1] * abv[1];
                o[2] = z[2] * abv[2];
            }
        }
    }
}

extern "C" void kernel_launch(void* const* d_in, const int* in_sizes, int n_in,
                              void* d_out, int out_size, void* d_ws, size_t ws_size,
                              hipStream_t stream) {
    (void)n_in; (void)out_size;
    const float* P  = (const float*)d_in[0];
    const float* WI = (const float*)d_in[1];
    const float* NV = (const float*)d_in[2];
    const float* AL = (const float*)d_in[3];
    const float* BE = (const float*)d_in[4];
    const float* RR = (const float*)d_in[5];
    const float* W0 = (const float*)d_in[6];
    const float* W1 = (const float*)d_in[7];
    const float* W2 = (const float*)d_in[8];
    const float* W3 = (const float*)d_in[9];
    const float* W4 = (const float*)d_in[10];
    const float* W5 = (const float*)d_in[11];
    const float* W6 = (const float*)d_in[12];
    f16*   ws  = (f16*)d_ws;
    float* Out = (float*)d_out;

    const int Bn = in_sizes[0] / 3;     // 1,048,576
    const int grid = Bn / SPB;          // 16384 blocks of 64 threads

    // ws_size fixed per session -> same path every call (graph-safe).
    if (ws_size >= WS_BYTES) {
        hipLaunchKernelGGL(pack_weights_kernel, dim3((WUNITS * 64 + 255) / 256),
                           dim3(256), 0, stream, W0, W1, W2, W3, W4, W5, W6, ws);
        hipLaunchKernelGGL((nrc_mlp_kernel<1>), dim3(grid), dim3(BLOCK), 0, stream,
                           P, WI, NV, AL, BE, RR, ws,
                           W0, W1, W2, W3, W4, W5, W6, Out);
    } else {
        hipLaunchKernelGGL((nrc_mlp_kernel<0>), dim3(grid), dim3(BLOCK), 0, stream,
                           P, WI, NV, AL, BE, RR, ws,
                           W0, W1, W2, W3, W4, W5, W6, Out);
    }
}

// Round 9
// 163.783 us; speedup vs baseline: 1.7478x; 1.0338x over previous
//
#include <hip/hip_runtime.h>

// NRC fused encode + 7-layer W=64 MLP. R9: K=32 MFMA register chaining.
//
// 16x16x32 f16 fragment maps (verified):
//   A[m=lane&15][k=(lane>>4)*8+j], B[k=(lane>>4)*8+j][n=lane&15],
//   D[row=(lane>>4)*4+r][col=lane&15]  (4 blocks mt: row=mt*16+q*4+r)
//
// Chaining: bf[kt] := concat(pk[2kt], pk[2kt+1]) where pk[mt]=relu(pack(acc[mt])).
// Register slot (kt,j) holds y[16*(2kt+(j>>2)) + 4q + (j&3)] but MFMA reads it
// as k-position x=32kt+8q+j. Fix entirely in the weight pack: columns of
// W1..W5,W6 permuted by tau(x)=32(x>>5)+16((x&7)>>2)+4((x>>3)&3)+(x&3).
// Layer 0 columns natural (encode emits natural order). Rows never permuted.
// => hidden layers run 8 MFMAs/tile of 16x16x32 (half the matrix-pipe time of
// R7/R8's 16 legacy 16x16x16) with ZERO LDS / cross-lane ops between layers.
//
// R8 post-mortem: VGPR=64 was sufficient, not squeezed; stalls = per-layer lazy
// weight loads + legacy-shape MFMA at full-shape cycle cost (52% MfmaUtil for
// half-rate math). R9 halves matrix-pipe demand and batches weight loads.

typedef _Float16 f16;
typedef f16 f16x2 __attribute__((ext_vector_type(2)));
typedef f16 f16x4 __attribute__((ext_vector_type(4)));
typedef f16 f16x8 __attribute__((ext_vector_type(8)));
typedef float f32x4 __attribute__((ext_vector_type(4)));

#define MFMA32(A, B, C) __builtin_amdgcn_mfma_f32_16x16x32_f16(A, B, C, 0, 0, 0)
#define LDS_FENCE() __asm__ volatile("" ::: "memory")

static constexpr int TILES = 4;       // 16-sample tiles per wave
static constexpr int WAVES = 2;       // independent waves per block (no barriers)
static constexpr int BLOCK = WAVES * 64;
static constexpr int SPB   = WAVES * 64;   // 128 samples per block

// d_ws pack: 50 units x 64 lanes x 16B = 51200 B.
// unit u<48: layer=u>>3, kt=(u&7)>>2, mt=u&3; lane(q,m) 8 f16:
//   j=0..7 -> W'[mt*16+m][kt*32+q*8+j], W' = col-permuted (tau) for layer>0.
// units 48,49: W6 rows m<3 (else 0), kt=u-48, cols tau-permuted.
static constexpr int    WUNITS   = 50;
static constexpr size_t WS_BYTES = (size_t)WUNITS * 64 * 16;   // 51200

__host__ __device__ __forceinline__ int tau(int x) {
    return (x & 32) + ((x & 7) >> 2) * 16 + ((x >> 3) & 3) * 4 + (x & 3);
}

__device__ __forceinline__ f16x2 pkh(float a, float b) {
    return __builtin_bit_cast(f16x2, __builtin_amdgcn_cvt_pkrtz(a, b));
}

__device__ __forceinline__ f16x8 pack8(const float* f) {
    f16x2 a = pkh(f[0], f[1]);
    f16x2 b = pkh(f[2], f[3]);
    f16x2 c = pkh(f[4], f[5]);
    f16x2 d = pkh(f[6], f[7]);
    f16x8 v;
    v[0] = a[0]; v[1] = a[1]; v[2] = b[0]; v[3] = b[1];
    v[4] = c[0]; v[5] = c[1]; v[6] = d[0]; v[7] = d[1];
    return v;
}

__device__ __forceinline__ f16x4 pack4(f32x4 v) {
    f16x2 a = pkh(v[0], v[1]);
    f16x2 b = pkh(v[2], v[3]);
    f16x4 r;
    r[0] = a[0]; r[1] = a[1]; r[2] = b[0]; r[3] = b[1];
    return r;
}

// atan2(y,x) / (2*pi)
__device__ __forceinline__ float fast_atan2_rev(float y, float x) {
    const float ax = __builtin_fabsf(x), ay = __builtin_fabsf(y);
    const float mx = fmaxf(ax, ay), mn = fminf(ax, ay);
    const float a = mn * __builtin_amdgcn_rcpf(fmaxf(mx, 1e-30f));
    const float s = a * a;
    float r = a * (0.99997726f + s * (-0.33262347f + s * (0.19354346f +
              s * (-0.11643287f + s * (0.05265332f - s * 0.01172120f)))));
    if (ay > ax) r = 1.5707963268f - r;
    if (x < 0.0f) r = 3.1415926536f - r;
    r = (y < 0.0f) ? -r : r;
    return r * 0.15915494309189535f;
}

// acos(x), |err| <= 6.8e-5 rad
__device__ __forceinline__ float fast_acos(float x) {
    const float ax = __builtin_fabsf(x);
    const float t = __builtin_amdgcn_sqrtf(1.0f - ax);
    const float p = t * (1.5707288f + ax * (-0.2121144f +
                    ax * (0.0742610f - ax * 0.0187293f)));
    return (x < 0.0f) ? (3.1415926536f - p) : p;
}

// one-blob: out[i]=exp(-8(x-c_i)^2) via exp ladder (2 transcendentals)
__device__ __forceinline__ void blob4(float x, float* out) {
    const float dx = x - 0.125f;
    const float E0 = __expf(-8.0f * dx * dx);
    const float R  = __expf(4.0f * dx);
    const float t1 = R * 0.60653066f;
    const float t2 = R * 0.22313016f;
    const float t3 = R * 0.082084999f;
    out[0] = E0;
    out[1] = E0 * t1;
    out[2] = out[1] * t2;
    out[3] = out[2] * t3;
}

__global__ __launch_bounds__(256, 1) void pack_weights_kernel(
    const float* __restrict__ W0, const float* __restrict__ W1,
    const float* __restrict__ W2, const float* __restrict__ W3,
    const float* __restrict__ W4, const float* __restrict__ W5,
    const float* __restrict__ W6, f16* __restrict__ ws)
{
    const int u = (int)blockIdx.x * 256 + threadIdx.x;
    if (u >= WUNITS * 64) return;
    const int lane = u & 63;
    const int unit = u >> 6;
    const int q = lane >> 4, m = lane & 15;
    f16x8 v;
    if (unit < 48) {
        const int l = unit >> 3, kt = (unit & 7) >> 2, mt = unit & 3;
        const float* Ws[6] = {W0, W1, W2, W3, W4, W5};
        const float* __restrict__ Wl = Ws[l];
#pragma unroll
        for (int j = 0; j < 8; ++j) {
            const int x = kt * 32 + q * 8 + j;
            const int src = (l == 0) ? x : tau(x);
            v[j] = (f16)Wl[(mt * 16 + m) * 64 + src];
        }
    } else {
        const int kt = unit - 48;
#pragma unroll
        for (int j = 0; j < 8; ++j) {
            const int src = tau(kt * 32 + q * 8 + j);
            v[j] = (m < 3) ? (f16)W6[m * 64 + src] : (f16)0.0f;
        }
    }
    *(f16x8*)(ws + unit * 512 + lane * 8) = v;
}

__device__ __forceinline__ f16x8 cat44(f16x4 a, f16x4 b) {
    return __builtin_shufflevector(a, b, 0, 1, 2, 3, 4, 5, 6, 7);
}

template<int PACKED>
__global__ __launch_bounds__(BLOCK, 4) void nrc_mlp_kernel(
    const float* __restrict__ P,  const float* __restrict__ WI,
    const float* __restrict__ NV, const float* __restrict__ AL,
    const float* __restrict__ BE, const float* __restrict__ RR,
    const f16*   __restrict__ ws,
    const float* __restrict__ W0, const float* __restrict__ W1,
    const float* __restrict__ W2, const float* __restrict__ W3,
    const float* __restrict__ W4, const float* __restrict__ W5,
    const float* __restrict__ W6, float* __restrict__ Out)
{
    // per-wave: 8192 B tile buffer (swizzled dword layout) + 1024 B ab
    __shared__ __attribute__((aligned(16))) unsigned char smem[WAVES * 9216];

    const int tid  = threadIdx.x;
    const int lane = tid & 63;
    const int w    = tid >> 6;
    const int q    = lane >> 4;
    const int m    = lane & 15;
    unsigned char* const hb  = smem + w * 9216;
    unsigned char* const abb = hb + 8192;

    const int wave_base = (int)blockIdx.x * SPB + w * 64;

    // ---- encode: one sample per lane ----
    {
        const int s = wave_base + lane;

        float pv[3], wv[3], nv[3], av[3], bv[3];
#pragma unroll
        for (int d = 0; d < 3; ++d) {
            pv[d] = P [s * 3 + d];
            wv[d] = WI[s * 3 + d];
            nv[d] = NV[s * 3 + d];
            av[d] = AL[s * 3 + d];
            bv[d] = BE[s * 3 + d];
        }
        const float rv = RR[s];

        float feat[64];
        // freq embed: base sin/cos at pi*p (revolutions) + exact angle doubling
#pragma unroll
        for (int d = 0; d < 3; ++d) {
            const float fr = __builtin_amdgcn_fractf(pv[d] * 0.5f);
            float sv = __builtin_amdgcn_sinf(fr);
            float cv = __builtin_amdgcn_cosf(fr);
            feat[d * 12 + 0] = sv;
            feat[d * 12 + 6] = cv;
#pragma unroll
            for (int k = 1; k < 6; ++k) {
                const float s2 = sv * sv;
                const float sc = sv * cv;
                cv = fmaf(-2.0f, s2, 1.0f);
                sv = sc + sc;
                feat[d * 12 + k]     = sv;
                feat[d * 12 + 6 + k] = cv;
            }
        }
#pragma unroll
        for (int which = 0; which < 2; ++which) {
            const float* dv = (which == 0) ? wv : nv;
            const int fo = 36 + which * 8;
            const float nr = __builtin_amdgcn_sqrtf(dv[0]*dv[0] + dv[1]*dv[1] + dv[2]*dv[2]) + 1e-8f;
            const float u  = fast_atan2_rev(dv[1], dv[0]) + 0.5f;
            float zc = dv[2] * __builtin_amdgcn_rcpf(nr);
            zc = fminf(fmaxf(zc, -1.0f + 1e-6f), 1.0f - 1e-6f);
            const float vv = fast_acos(zc) * 0.3183098861837907f;
            blob4(u,  &feat[fo]);
            blob4(vv, &feat[fo + 4]);
        }
        blob4(1.0f - __expf(-rv), &feat[52]);

        feat[56] = av[0]; feat[57] = av[1]; feat[58] = av[2];
        feat[59] = bv[0]; feat[60] = bv[1]; feat[61] = bv[2];
        feat[62] = 1.0f;  feat[63] = 1.0f;

        f32x4 abv;
        abv[0] = av[0] + bv[0]; abv[1] = av[1] + bv[1];
        abv[2] = av[2] + bv[2]; abv[3] = 0.0f;
        *(f32x4*)(abb + lane * 16) = abv;

        // features -> LDS: [tile=lane>>4][m][dword-slot], slot=(D+4m)&31
        // (natural dword D holds features 2D,2D+1); groups of 4 contiguous.
        const int te = lane >> 4, me = lane & 15;
        unsigned char* const tb = hb + te * 2048 + me * 128;
#pragma unroll
        for (int g = 0; g < 8; ++g) {
            const int slot0 = (4 * g + 4 * me) & 31;
            *(f16x8*)(tb + slot0 * 4) = pack8(&feat[g * 8]);
        }
    }
    LDS_FENCE();   // encode writes ordered before frag reads (same wave)

    // ---- B-frags, K=32 natural layout: dwords D=16kt+4q..+3 of col m ----
    f16x8 bf[TILES][2];
#pragma unroll
    for (int t = 0; t < TILES; ++t) {
#pragma unroll
        for (int kt = 0; kt < 2; ++kt) {
            const int s0 = (16 * kt + 4 * q + 4 * m) & 31;
            bf[t][kt] = *(const f16x8*)(hb + t * 2048 + m * 128 + s0 * 4);
        }
    }

    const f16* const wbase = ws + (size_t)lane * 8;
    const float* const Ws[6] = {W0, W1, W2, W3, W4, W5};
    const f16x4 zero4 = {(f16)0.0f, (f16)0.0f, (f16)0.0f, (f16)0.0f};

    // ---- hidden layers: pure-register chain, 8 MFMAs(16x16x32)/tile ----
#pragma unroll
    for (int layer = 0; layer < 6; ++layer) {
        f16x8 wa[8];   // frag index f = kt*4+mt
        if (PACKED) {
#pragma unroll
            for (int f = 0; f < 8; ++f)
                wa[f] = *(const f16x8*)(wbase + (layer * 8 + f) * 512);
        } else {
            const float* __restrict__ Wl = Ws[layer];
#pragma unroll
            for (int kt = 0; kt < 2; ++kt)
#pragma unroll
                for (int mt = 0; mt < 4; ++mt) {
                    float tv[8];
#pragma unroll
                    for (int j = 0; j < 8; ++j) {
                        const int x = kt * 32 + q * 8 + j;
                        tv[j] = Wl[(mt * 16 + m) * 64 + (layer == 0 ? x : tau(x))];
                    }
                    wa[kt * 4 + mt] = pack8(tv);
                }
        }

#pragma unroll
        for (int t = 0; t < TILES; ++t) {
            f32x4 acc[4];
#pragma unroll
            for (int mt = 0; mt < 4; ++mt) {
                f32x4 z = {0.0f, 0.0f, 0.0f, 0.0f};
                z = MFMA32(wa[mt],     bf[t][0], z);
                z = MFMA32(wa[4 + mt], bf[t][1], z);
                acc[mt] = z;
            }
            f16x4 pk[4];
#pragma unroll
            for (int mt = 0; mt < 4; ++mt)
                pk[mt] = __builtin_elementwise_max(pack4(acc[mt]), zero4);
            bf[t][0] = cat44(pk[0], pk[1]);   // tau absorbed in next layer's cols
            bf[t][1] = cat44(pk[2], pk[3]);
        }
    }

    // ---- final layer (W6, tau-permuted cols) + scale by (alpha+beta) ----
    {
        f16x8 w6f[2];
        if (PACKED) {
            w6f[0] = *(const f16x8*)(wbase + 48 * 512);
            w6f[1] = *(const f16x8*)(wbase + 49 * 512);
        } else {
#pragma unroll
            for (int kt = 0; kt < 2; ++kt) {
                float tv[8];
#pragma unroll
                for (int j = 0; j < 8; ++j) {
                    const int src = tau(kt * 32 + q * 8 + j);
                    tv[j] = (m < 3) ? W6[m * 64 + src] : 0.0f;
                }
                w6f[kt] = pack8(tv);
            }
        }
#pragma unroll
        for (int t = 0; t < TILES; ++t) {
            f32x4 z = {0.0f, 0.0f, 0.0f, 0.0f};
            z = MFMA32(w6f[0], bf[t][0], z);
            z = MFMA32(w6f[1], bf[t][1], z);
            const f32x4 abv = *(const f32x4*)(abb + (t * 16 + m) * 16);
            if (lane < 16) {   // q==0: D rows r=0..2 = output channels, col m
                const int s = wave_base + t * 16 + m;
                float* o = Out + s * 3;
                o[0] = z[0] * abv[0];
                o[1] = z[1] * abv[1];
                o[2] = z[2] * abv[2];
            }
        }
    }
}

extern "C" void kernel_launch(void* const* d_in, const int* in_sizes, int n_in,
                              void* d_out, int out_size, void* d_ws, size_t ws_size,
                              hipStream_t stream) {
    (void)n_in; (void)out_size;
    const float* P  = (const float*)d_in[0];
    const float* WI = (const float*)d_in[1];
    const float* NV = (const float*)d_in[2];
    const float* AL = (const float*)d_in[3];
    const float* BE = (const float*)d_in[4];
    const float* RR = (const float*)d_in[5];
    const float* W0 = (const float*)d_in[6];
    const float* W1 = (const float*)d_in[7];
    const float* W2 = (const float*)d_in[8];
    const float* W3 = (const float*)d_in[9];
    const float* W4 = (const float*)d_in[10];
    const float* W5 = (const float*)d_in[11];
    const float* W6 = (const float*)d_in[12];
    f16*   ws  = (f16*)d_ws;
    float* Out = (float*)d_out;

    const int Bn = in_sizes[0] / 3;     // 1,048,576
    const int grid = Bn / SPB;          // 8192 blocks of 128 threads

    // ws_size fixed per session -> same path every call (graph-safe).
    if (ws_size >= WS_BYTES) {
        hipLaunchKernelGGL(pack_weights_kernel, dim3((WUNITS * 64 + 255) / 256),
                           dim3(256), 0, stream, W0, W1, W2, W3, W4, W5, W6, ws);
        hipLaunchKernelGGL((nrc_mlp_kernel<1>), dim3(grid), dim3(BLOCK), 0, stream,
                           P, WI, NV, AL, BE, RR, ws,
                           W0, W1, W2, W3, W4, W5, W6, Out);
    } else {
        hipLaunchKernelGGL((nrc_mlp_kernel<0>), dim3(grid), dim3(BLOCK), 0, stream,
                           P, WI, NV, AL, BE, RR, ws,
                           W0, W1, W2, W3, W4, W5, W6, Out);
    }
}

// Round 10
// 157.801 us; speedup vs baseline: 1.8140x; 1.0379x over previous
//
#include <hip/hip_runtime.h>

// NRC fused encode + 7-layer W=64 MLP. R10 = R9 (K=32 register chaining) with
// the spill fixed: __launch_bounds__(128,2) -> 256-VGPR cap.
//
// R9 post-mortem: WRITE_SIZE 12.3->29.8 MB, FETCH +3 MB, VGPR=64. Spill
// signature (spill stores evicted from L2 to HBM; reloads hit L2). Allocator
// pinned 64 regs (8-waves/EU heuristic) although the steady-state live set is
// ~90 (bf 32 + wa 32 + acc 16 + addrs). (128,2) lets it allocate ~96-128.
//
// 16x16x32 f16 fragment maps (verified):
//   A[m=lane&15][k=(lane>>4)*8+j], B[k=(lane>>4)*8+j][n=lane&15],
//   D[row=(lane>>4)*4+r][col=lane&15]  (4 blocks mt: row=mt*16+q*4+r)
// Chaining: bf[kt]=concat(relu(pack(acc[2kt])), relu(pack(acc[2kt+1]))); the
// k-index mismatch is absorbed by permuting W1..W5,W6 columns with
// tau(x)=32(x>>5)+16((x&7)>>2)+4((x>>3)&3)+(x&3) at pack time. Zero LDS and
// zero cross-lane ops between layers.

typedef _Float16 f16;
typedef f16 f16x2 __attribute__((ext_vector_type(2)));
typedef f16 f16x4 __attribute__((ext_vector_type(4)));
typedef f16 f16x8 __attribute__((ext_vector_type(8)));
typedef float f32x4 __attribute__((ext_vector_type(4)));

#define MFMA32(A, B, C) __builtin_amdgcn_mfma_f32_16x16x32_f16(A, B, C, 0, 0, 0)
#define LDS_FENCE() __asm__ volatile("" ::: "memory")

static constexpr int TILES = 4;       // 16-sample tiles per wave
static constexpr int WAVES = 2;       // independent waves per block (no barriers)
static constexpr int BLOCK = WAVES * 64;
static constexpr int SPB   = WAVES * 64;   // 128 samples per block

// d_ws pack: 50 units x 64 lanes x 16B = 51200 B.
// unit u<48: layer=u>>3, kt=(u&7)>>2, mt=u&3; lane(q,m) 8 f16:
//   j=0..7 -> W'[mt*16+m][kt*32+q*8+j], W' = col-permuted (tau) for layer>0.
// units 48,49: W6 rows m<3 (else 0), kt=u-48, cols tau-permuted.
static constexpr int    WUNITS   = 50;
static constexpr size_t WS_BYTES = (size_t)WUNITS * 64 * 16;   // 51200

__host__ __device__ __forceinline__ int tau(int x) {
    return (x & 32) + ((x & 7) >> 2) * 16 + ((x >> 3) & 3) * 4 + (x & 3);
}

__device__ __forceinline__ f16x2 pkh(float a, float b) {
    return __builtin_bit_cast(f16x2, __builtin_amdgcn_cvt_pkrtz(a, b));
}

__device__ __forceinline__ f16x8 pack8(const float* f) {
    f16x2 a = pkh(f[0], f[1]);
    f16x2 b = pkh(f[2], f[3]);
    f16x2 c = pkh(f[4], f[5]);
    f16x2 d = pkh(f[6], f[7]);
    f16x8 v;
    v[0] = a[0]; v[1] = a[1]; v[2] = b[0]; v[3] = b[1];
    v[4] = c[0]; v[5] = c[1]; v[6] = d[0]; v[7] = d[1];
    return v;
}

__device__ __forceinline__ f16x4 pack4(f32x4 v) {
    f16x2 a = pkh(v[0], v[1]);
    f16x2 b = pkh(v[2], v[3]);
    f16x4 r;
    r[0] = a[0]; r[1] = a[1]; r[2] = b[0]; r[3] = b[1];
    return r;
}

// atan2(y,x) / (2*pi)
__device__ __forceinline__ float fast_atan2_rev(float y, float x) {
    const float ax = __builtin_fabsf(x), ay = __builtin_fabsf(y);
    const float mx = fmaxf(ax, ay), mn = fminf(ax, ay);
    const float a = mn * __builtin_amdgcn_rcpf(fmaxf(mx, 1e-30f));
    const float s = a * a;
    float r = a * (0.99997726f + s * (-0.33262347f + s * (0.19354346f +
              s * (-0.11643287f + s * (0.05265332f - s * 0.01172120f)))));
    if (ay > ax) r = 1.5707963268f - r;
    if (x < 0.0f) r = 3.1415926536f - r;
    r = (y < 0.0f) ? -r : r;
    return r * 0.15915494309189535f;
}

// acos(x), |err| <= 6.8e-5 rad
__device__ __forceinline__ float fast_acos(float x) {
    const float ax = __builtin_fabsf(x);
    const float t = __builtin_amdgcn_sqrtf(1.0f - ax);
    const float p = t * (1.5707288f + ax * (-0.2121144f +
                    ax * (0.0742610f - ax * 0.0187293f)));
    return (x < 0.0f) ? (3.1415926536f - p) : p;
}

// one-blob: out[i]=exp(-8(x-c_i)^2) via exp ladder (2 transcendentals)
__device__ __forceinline__ void blob4(float x, float* out) {
    const float dx = x - 0.125f;
    const float E0 = __expf(-8.0f * dx * dx);
    const float R  = __expf(4.0f * dx);
    const float t1 = R * 0.60653066f;
    const float t2 = R * 0.22313016f;
    const float t3 = R * 0.082084999f;
    out[0] = E0;
    out[1] = E0 * t1;
    out[2] = out[1] * t2;
    out[3] = out[2] * t3;
}

__global__ __launch_bounds__(256, 1) void pack_weights_kernel(
    const float* __restrict__ W0, const float* __restrict__ W1,
    const float* __restrict__ W2, const float* __restrict__ W3,
    const float* __restrict__ W4, const float* __restrict__ W5,
    const float* __restrict__ W6, f16* __restrict__ ws)
{
    const int u = (int)blockIdx.x * 256 + threadIdx.x;
    if (u >= WUNITS * 64) return;
    const int lane = u & 63;
    const int unit = u >> 6;
    const int q = lane >> 4, m = lane & 15;
    f16x8 v;
    if (unit < 48) {
        const int l = unit >> 3, kt = (unit & 7) >> 2, mt = unit & 3;
        const float* Ws[6] = {W0, W1, W2, W3, W4, W5};
        const float* __restrict__ Wl = Ws[l];
#pragma unroll
        for (int j = 0; j < 8; ++j) {
            const int x = kt * 32 + q * 8 + j;
            const int src = (l == 0) ? x : tau(x);
            v[j] = (f16)Wl[(mt * 16 + m) * 64 + src];
        }
    } else {
        const int kt = unit - 48;
#pragma unroll
        for (int j = 0; j < 8; ++j) {
            const int src = tau(kt * 32 + q * 8 + j);
            v[j] = (m < 3) ? (f16)W6[m * 64 + src] : (f16)0.0f;
        }
    }
    *(f16x8*)(ws + unit * 512 + lane * 8) = v;
}

__device__ __forceinline__ f16x8 cat44(f16x4 a, f16x4 b) {
    return __builtin_shufflevector(a, b, 0, 1, 2, 3, 4, 5, 6, 7);
}

template<int PACKED>
__global__ __launch_bounds__(BLOCK, 2) void nrc_mlp_kernel(
    const float* __restrict__ P,  const float* __restrict__ WI,
    const float* __restrict__ NV, const float* __restrict__ AL,
    const float* __restrict__ BE, const float* __restrict__ RR,
    const f16*   __restrict__ ws,
    const float* __restrict__ W0, const float* __restrict__ W1,
    const float* __restrict__ W2, const float* __restrict__ W3,
    const float* __restrict__ W4, const float* __restrict__ W5,
    const float* __restrict__ W6, float* __restrict__ Out)
{
    // per-wave: 8192 B tile buffer (swizzled dword layout) + 1024 B ab
    __shared__ __attribute__((aligned(16))) unsigned char smem[WAVES * 9216];

    const int tid  = threadIdx.x;
    const int lane = tid & 63;
    const int w    = tid >> 6;
    const int q    = lane >> 4;
    const int m    = lane & 15;
    unsigned char* const hb  = smem + w * 9216;
    unsigned char* const abb = hb + 8192;

    const int wave_base = (int)blockIdx.x * SPB + w * 64;

    // ---- encode: one sample per lane ----
    {
        const int s = wave_base + lane;

        float pv[3], wv[3], nv[3], av[3], bv[3];
#pragma unroll
        for (int d = 0; d < 3; ++d) {
            pv[d] = P [s * 3 + d];
            wv[d] = WI[s * 3 + d];
            nv[d] = NV[s * 3 + d];
            av[d] = AL[s * 3 + d];
            bv[d] = BE[s * 3 + d];
        }
        const float rv = RR[s];

        float feat[64];
        // freq embed: base sin/cos at pi*p (revolutions) + exact angle doubling
#pragma unroll
        for (int d = 0; d < 3; ++d) {
            const float fr = __builtin_amdgcn_fractf(pv[d] * 0.5f);
            float sv = __builtin_amdgcn_sinf(fr);
            float cv = __builtin_amdgcn_cosf(fr);
            feat[d * 12 + 0] = sv;
            feat[d * 12 + 6] = cv;
#pragma unroll
            for (int k = 1; k < 6; ++k) {
                const float s2 = sv * sv;
                const float sc = sv * cv;
                cv = fmaf(-2.0f, s2, 1.0f);
                sv = sc + sc;
                feat[d * 12 + k]     = sv;
                feat[d * 12 + 6 + k] = cv;
            }
        }
#pragma unroll
        for (int which = 0; which < 2; ++which) {
            const float* dv = (which == 0) ? wv : nv;
            const int fo = 36 + which * 8;
            const float nr = __builtin_amdgcn_sqrtf(dv[0]*dv[0] + dv[1]*dv[1] + dv[2]*dv[2]) + 1e-8f;
            const float u  = fast_atan2_rev(dv[1], dv[0]) + 0.5f;
            float zc = dv[2] * __builtin_amdgcn_rcpf(nr);
            zc = fminf(fmaxf(zc, -1.0f + 1e-6f), 1.0f - 1e-6f);
            const float vv = fast_acos(zc) * 0.3183098861837907f;
            blob4(u,  &feat[fo]);
            blob4(vv, &feat[fo + 4]);
        }
        blob4(1.0f - __expf(-rv), &feat[52]);

        feat[56] = av[0]; feat[57] = av[1]; feat[58] = av[2];
        feat[59] = bv[0]; feat[60] = bv[1]; feat[61] = bv[2];
        feat[62] = 1.0f;  feat[63] = 1.0f;

        f32x4 abv;
        abv[0] = av[0] + bv[0]; abv[1] = av[1] + bv[1];
        abv[2] = av[2] + bv[2]; abv[3] = 0.0f;
        *(f32x4*)(abb + lane * 16) = abv;

        // features -> LDS: [tile=lane>>4][m][dword-slot], slot=(D+4m)&31
        // (natural dword D holds features 2D,2D+1); groups of 4 contiguous.
        const int te = lane >> 4, me = lane & 15;
        unsigned char* const tb = hb + te * 2048 + me * 128;
#pragma unroll
        for (int g = 0; g < 8; ++g) {
            const int slot0 = (4 * g + 4 * me) & 31;
            *(f16x8*)(tb + slot0 * 4) = pack8(&feat[g * 8]);
        }
    }
    LDS_FENCE();   // encode writes ordered before frag reads (same wave)

    // ---- B-frags, K=32 natural layout: dwords D=16kt+4q..+3 of col m ----
    f16x8 bf[TILES][2];
#pragma unroll
    for (int t = 0; t < TILES; ++t) {
#pragma unroll
        for (int kt = 0; kt < 2; ++kt) {
            const int s0 = (16 * kt + 4 * q + 4 * m) & 31;
            bf[t][kt] = *(const f16x8*)(hb + t * 2048 + m * 128 + s0 * 4);
        }
    }

    const f16* const wbase = ws + (size_t)lane * 8;
    const float* const Ws[6] = {W0, W1, W2, W3, W4, W5};
    const f16x4 zero4 = {(f16)0.0f, (f16)0.0f, (f16)0.0f, (f16)0.0f};

    // ---- hidden layers: pure-register chain, 8 MFMAs(16x16x32)/tile ----
#pragma unroll
    for (int layer = 0; layer < 6; ++layer) {
        f16x8 wa[8];   // frag index f = kt*4+mt
        if (PACKED) {
#pragma unroll
            for (int f = 0; f < 8; ++f)
                wa[f] = *(const f16x8*)(wbase + (layer * 8 + f) * 512);
        } else {
            const float* __restrict__ Wl = Ws[layer];
#pragma unroll
            for (int kt = 0; kt < 2; ++kt)
#pragma unroll
                for (int mt = 0; mt < 4; ++mt) {
                    float tv[8];
#pragma unroll
                    for (int j = 0; j < 8; ++j) {
                        const int x = kt * 32 + q * 8 + j;
                        tv[j] = Wl[(mt * 16 + m) * 64 + (layer == 0 ? x : tau(x))];
                    }
                    wa[kt * 4 + mt] = pack8(tv);
                }
        }

#pragma unroll
        for (int t = 0; t < TILES; ++t) {
            f32x4 acc[4];
#pragma unroll
            for (int mt = 0; mt < 4; ++mt) {
                f32x4 z = {0.0f, 0.0f, 0.0f, 0.0f};
                z = MFMA32(wa[mt],     bf[t][0], z);
                z = MFMA32(wa[4 + mt], bf[t][1], z);
                acc[mt] = z;
            }
            f16x4 pk[4];
#pragma unroll
            for (int mt = 0; mt < 4; ++mt)
                pk[mt] = __builtin_elementwise_max(pack4(acc[mt]), zero4);
            bf[t][0] = cat44(pk[0], pk[1]);   // tau absorbed in next layer's cols
            bf[t][1] = cat44(pk[2], pk[3]);
        }
    }

    // ---- final layer (W6, tau-permuted cols) + scale by (alpha+beta) ----
    {
        f16x8 w6f[2];
        if (PACKED) {
            w6f[0] = *(const f16x8*)(wbase + 48 * 512);
            w6f[1] = *(const f16x8*)(wbase + 49 * 512);
        } else {
#pragma unroll
            for (int kt = 0; kt < 2; ++kt) {
                float tv[8];
#pragma unroll
                for (int j = 0; j < 8; ++j) {
                    const int src = tau(kt * 32 + q * 8 + j);
                    tv[j] = (m < 3) ? W6[m * 64 + src] : 0.0f;
                }
                w6f[kt] = pack8(tv);
            }
        }
#pragma unroll
        for (int t = 0; t < TILES; ++t) {
            f32x4 z = {0.0f, 0.0f, 0.0f, 0.0f};
            z = MFMA32(w6f[0], bf[t][0], z);
            z = MFMA32(w6f[1], bf[t][1], z);
            const f32x4 abv = *(const f32x4*)(abb + (t * 16 + m) * 16);
            if (lane < 16) {   // q==0: D rows r=0..2 = output channels, col m
                const int s = wave_base + t * 16 + m;
                float* o = Out + s * 3;
                o[0] = z[0] * abv[0];
                o[1] = z[1] * abv[1];
                o[2] = z[2] * abv[2];
            }
        }
    }
}

extern "C" void kernel_launch(void* const* d_in, const int* in_sizes, int n_in,
                              void* d_out, int out_size, void* d_ws, size_t ws_size,
                              hipStream_t stream) {
    (void)n_in; (void)out_size;
    const float* P  = (const float*)d_in[0];
    const float* WI = (const float*)d_in[1];
    const float* NV = (const float*)d_in[2];
    const float* AL = (const float*)d_in[3];
    const float* BE = (const float*)d_in[4];
    const float* RR = (const float*)d_in[5];
    const float* W0 = (const float*)d_in[6];
    const float* W1 = (const float*)d_in[7];
    const float* W2 = (const float*)d_in[8];
    const float* W3 = (const float*)d_in[9];
    const float* W4 = (const float*)d_in[10];
    const float* W5 = (const float*)d_in[11];
    const float* W6 = (const float*)d_in[12];
    f16*   ws  = (f16*)d_ws;
    float* Out = (float*)d_out;

    const int Bn = in_sizes[0] / 3;     // 1,048,576
    const int grid = Bn / SPB;          // 8192 blocks of 128 threads

    // ws_size fixed per session -> same path every call (graph-safe).
    if (ws_size >= WS_BYTES) {
        hipLaunchKernelGGL(pack_weights_kernel, dim3((WUNITS * 64 + 255) / 256),
                           dim3(256), 0, stream, W0, W1, W2, W3, W4, W5, W6, ws);
        hipLaunchKernelGGL((nrc_mlp_kernel<1>), dim3(grid), dim3(BLOCK), 0, stream,
                           P, WI, NV, AL, BE, RR, ws,
                           W0, W1, W2, W3, W4, W5, W6, Out);
    } else {
        hipLaunchKernelGGL((nrc_mlp_kernel<0>), dim3(grid), dim3(BLOCK), 0, stream,
                           P, WI, NV, AL, BE, RR, ws,
                           W0, W1, W2, W3, W4, W5, W6, Out);
    }
}